// Round 1
// 705.108 us; speedup vs baseline: 1.0463x; 1.0463x over previous
//
#include <hip/hip_runtime.h>

#define N_NODES 131072
#define N_EDGES 524288
#define K_TOP   65536
#define LN_EPS  1e-5f

typedef unsigned int u32;
typedef unsigned short u16;
typedef unsigned long long u64;

typedef __attribute__((ext_vector_type(8))) short bf8;
typedef __attribute__((ext_vector_type(4))) float f4;

// ---- ws layout (requires ws >= 40 MB) ----
#define ST_OFF    0             // SelState (~52KB, reserve 64KB)
#define CANON_OFF (64u<<10)     // canon + transposed weights (~461KB) -> [64K, 576K)
#define PART_OFF  (576u<<10)    // 256x256 u32 partial hists (radix); later BSUM (512B)
#define KEYS_OFF  (1u<<20)      // keys u64[N] = 1MB; after k_mark reused as DEG/CUR u32[N]
#define TVAL_OFF  (2u<<20)      // N f32 = 512KB
#define KEPT_OFF  ((2u<<20)+(512u<<10)) // N u32 = 512KB
#define SBUF_OFF  (3u<<20)      // message buffer S/S2: N x 64 u32 = 32MB -> [3M,35M)
#define OFF_OFF   (35u<<20)     // CSR off u32[N+1] = 512KB+4
#define ADJ_OFF   (36u<<20)     // CSR adj u32[2E] = 4MB -> ends 40M

// canonical parameter block offsets (bf16 elements)
#define C_DW1 0
#define C_DB1 16384
#define C_DW2 16512
#define C_DB2 32896
#define C_DW3 33024
#define C_DB3 49408
#define C_DG  49536
#define C_DBE 49664
#define C_UW1 49792
#define C_UB1 82560
#define C_UW2 82688
#define C_UB2 99072
#define C_UW3 99200
#define C_UB3 115584
#define C_UG  115712
#define C_UBE 115840
#define C_TOT 115968
// transposed weights WT[n][k] appended
#define CT_DW1 115968
#define CT_DW2 132352
#define CT_DW3 148736
#define CT_UW1 165120   /* [128][256] */
#define CT_UW2 197888
#define CT_UW3 214272
#define CT_TOT 230656
#define T_REGION (CT_TOT - CT_DW1)   /* 114688 */

__device__ __forceinline__ float bflo(u32 u){ return __uint_as_float(u << 16); }
__device__ __forceinline__ float bfhi(u32 u){ return __uint_as_float(u & 0xFFFF0000u); }
__device__ __forceinline__ float bf2f(u16 v){ return __uint_as_float(((u32)v) << 16); }
__device__ __forceinline__ u32 f2bf(float f){
  u32 u = __float_as_uint(f);
  return (u + 0x7FFFu + ((u >> 16) & 1u)) >> 16;
}
__device__ __forceinline__ float gelu_f(float x){
  return 0.5f * x * (1.0f + erff(x * 0.7071067811865476f));
}

// wave-level 16x128 GEMM step over K=128: in_s rows [m0..m0+16), WT rows = out cols.
__device__ __forceinline__ void wave_gemm(const u16* in_s, const u16* w_s,
                                          int m0, int mn, int quad, f4 acc[8]){
  #pragma unroll
  for (int s = 0; s < 4; s++){
    bf8 a = *(const bf8*)(in_s + (m0 + mn) * 136 + s * 32 + quad * 8);
    #pragma unroll
    for (int j = 0; j < 8; j++){
      bf8 b = *(const bf8*)(w_s + (j * 16 + mn) * 136 + s * 32 + quad * 8);
      acc[j] = __builtin_amdgcn_mfma_f32_16x16x32_bf16(a, b, acc[j], 0, 0, 0);
    }
  }
}

struct SelState {
  u64 prefix;
  u32 krem, eqcnt;
  int is_f32;
  u32 pad;
  double inv_norm;
  u32 eqlist[4096];
  u64 eqkey[4096];
};

struct P16 { const void* q[16]; };

// ---------------- dtype detection ----------------
__global__ void k_detect(const u32* __restrict__ xw, SelState* st){
  int t = threadIdx.x;
  int cnt = 0;
  for (int i = t; i < 4096; i += 256){
    u32 w = xw[(size_t)i * 2048];
    u32 e = (w >> 23) & 0xFFu;
    if (e >= 97u && e <= 135u) cnt++;
  }
  __shared__ int sh[256];
  sh[t] = cnt; __syncthreads();
  for (int o = 128; o > 0; o >>= 1){ if (t < o) sh[t] += sh[t+o]; __syncthreads(); }
  if (t == 0) st->is_f32 = (sh[0] >= 3072) ? 1 : 0;
}

__global__ void k_init(SelState* st){
  if (threadIdx.x == 0){ st->prefix = 0; st->krem = K_TOP; st->eqcnt = 0; }
}

__global__ void k_canon(P16 ps, const SelState* __restrict__ st, u16* __restrict__ canon){
  const int off[17] = {C_DW1,C_DB1,C_DW2,C_DB2,C_DW3,C_DB3,C_DG,C_DBE,
                       C_UW1,C_UB1,C_UW2,C_UB2,C_UW3,C_UB3,C_UG,C_UBE,C_TOT};
  int i = blockIdx.x * 256 + threadIdx.x;
  if (i >= C_TOT) return;
  int seg = 0;
  #pragma unroll
  for (int s2 = 0; s2 < 16; s2++) if (i >= off[s2+1]) seg = s2 + 1;
  int j = i - off[seg];
  if (st->is_f32) canon[i] = (u16)f2bf(((const float*)ps.q[seg])[j]);
  else            canon[i] = ((const u16*)ps.q[seg])[j];
}

// build transposed weights WT[n][k] from canon W[k][n] (N==128 for all)
__global__ void k_canon_t(u16* __restrict__ canon){
  const int src[6] = {C_DW1, C_DW2, C_DW3, C_UW1, C_UW2, C_UW3};
  const int dst[7] = {CT_DW1, CT_DW2, CT_DW3, CT_UW1, CT_UW2, CT_UW3, CT_TOT};
  int i = blockIdx.x * 256 + threadIdx.x;
  if (i >= T_REGION) return;
  int g = CT_DW1 + i;
  int seg = 0;
  #pragma unroll
  for (int s2 = 0; s2 < 6; s2++) if (g >= dst[s2+1]) seg = s2 + 1;
  int loc = g - dst[seg];
  int K = (seg == 3) ? 256 : 128;
  int n = loc / K, k = loc % K;
  canon[g] = canon[src[seg] + k * 128 + n];
}

__global__ void k_pnorm(const void* __restrict__ p, SelState* st){
  int t = threadIdx.x;
  float pv = st->is_f32 ? ((const float*)p)[t] : bf2f(((const u16*)p)[t]);
  __shared__ double sh[128];
  sh[t] = (double)pv * (double)pv;
  __syncthreads();
  for (int o = 64; o > 0; o >>= 1){ if (t < o) sh[t] += sh[t+o]; __syncthreads(); }
  if (t == 0) st->inv_norm = 1.0 / sqrt(sh[0]);
}

__global__ __launch_bounds__(256) void k_score(const void* __restrict__ xraw, const void* __restrict__ praw,
                        const SelState* __restrict__ st,
                        u64* __restrict__ keys, float* __restrict__ tval){
  int t = threadIdx.x, lane = t & 63, w = t >> 6;
  int n = blockIdx.x * 4 + w;
  double d;
  if (st->is_f32){
    const float* xf = (const float*)xraw + (size_t)n * 128;
    const float* pf = (const float*)praw;
    d = (double)xf[lane] * (double)pf[lane]
      + (double)xf[64 + lane] * (double)pf[64 + lane];
  } else {
    const u32* xw = (const u32*)xraw + (size_t)n * 64;
    const u32* pw = (const u32*)praw;
    u32 xx = xw[lane], pv = pw[lane];
    d = (double)bflo(xx) * (double)bflo(pv) + (double)bfhi(xx) * (double)bfhi(pv);
  }
  for (int o = 32; o > 0; o >>= 1) d += __shfl_down(d, o, 64);
  if (lane == 0){
    double sc = d * st->inv_norm;
    u64 u = (u64)__double_as_longlong(sc);
    u64 key = (u & 0x8000000000000000ULL) ? ~u : (u | 0x8000000000000000ULL);
    keys[n] = key;
    tval[n] = tanhf((float)sc);
  }
}

// ---------------- contention-free 4-pass radix select (top 32 bits) ----------------
__global__ __launch_bounds__(256) void k_histp(const u64* __restrict__ keys,
                                               const SelState* __restrict__ st,
                                               u32* __restrict__ partial, int pass){
  __shared__ u32 h[256];
  int t = threadIdx.x;
  h[t] = 0;
  __syncthreads();
  u64 pref = st->prefix;
  int sh_d = 56 - 8 * pass;
  for (int n = blockIdx.x * 256 + t; n < N_NODES; n += 256 * 256){
    u64 k = keys[n];
    bool m = (pass == 0) ? true : ((k >> (sh_d + 8)) == pref);
    if (m) atomicAdd(&h[(u32)((k >> sh_d) & 255)], 1u);
  }
  __syncthreads();
  partial[blockIdx.x * 256 + t] = h[t];
}

__global__ void k_scanp(const u32* __restrict__ partial, SelState* st){
  __shared__ u32 tot[256];
  int t = threadIdx.x;
  u32 s = 0;
  for (int b = 0; b < 256; b++) s += partial[b * 256 + t];
  tot[t] = s;
  __syncthreads();
  if (t == 0){
    u32 target = st->krem;
    u32 cum = 0; int chosen = 255;
    for (int b = 255; b >= 0; b--){
      if (cum + tot[b] >= target){ chosen = b; break; }
      cum += tot[b];
    }
    st->prefix = (st->prefix << 8) | (u64)(u32)chosen;
    st->krem = target - cum;
  }
}

__global__ void k_mark(const u64* __restrict__ keys, SelState* st, u32* __restrict__ kept){
  int n = blockIdx.x * blockDim.x + threadIdx.x;
  u64 k = keys[n];
  u32 t32 = (u32)(k >> 32);
  u32 T = (u32)st->prefix;
  kept[n] = (t32 > T) ? 1u : 0u;
  if (t32 == T){
    u32 i = atomicAdd(&st->eqcnt, 1u);
    if (i < 4096){ st->eqlist[i] = (u32)n; st->eqkey[i] = k; }
  }
}

__global__ void k_tie(SelState* st, u32* __restrict__ kept){
  u32 m = st->eqcnt; if (m > 4096) m = 4096;
  u32 r = st->krem;
  for (u32 i = threadIdx.x; i < m; i += blockDim.x){
    u64 ki = st->eqkey[i]; u32 ii = st->eqlist[i];
    u32 rank = 0;
    for (u32 j = 0; j < m; j++){
      u64 kj = st->eqkey[j];
      rank += (kj > ki || (kj == ki && st->eqlist[j] < ii)) ? 1u : 0u;
    }
    if (rank < r) kept[ii] = 1u;
  }
}

// ---------------- CSR build (symmetrized adjacency) ----------------
__global__ __launch_bounds__(256) void k_deg(const int* __restrict__ se, const int* __restrict__ re,
                                             u32* __restrict__ deg){
  int e = blockIdx.x * 256 + threadIdx.x;
  int s = se[e], r = re[e];
  atomicAdd(&deg[s], 1u);
  atomicAdd(&deg[r], 1u);
}

__global__ __launch_bounds__(256) void k_scan1(const u32* __restrict__ deg, u32* __restrict__ bsum){
  __shared__ u32 sh[256];
  int t = threadIdx.x;
  int base = blockIdx.x * 1024 + t * 4;
  u32 s = deg[base] + deg[base+1] + deg[base+2] + deg[base+3];
  sh[t] = s; __syncthreads();
  for (int o = 128; o > 0; o >>= 1){ if (t < o) sh[t] += sh[t+o]; __syncthreads(); }
  if (t == 0) bsum[blockIdx.x] = sh[0];
}

__global__ void k_scan2(u32* __restrict__ bsum){
  __shared__ u32 sh[128];
  int t = threadIdx.x;            // 128 threads
  u32 v = bsum[t];
  sh[t] = v; __syncthreads();
  for (int o = 1; o < 128; o <<= 1){
    u32 x = (t >= o) ? sh[t-o] : 0u;
    __syncthreads();
    sh[t] += x;
    __syncthreads();
  }
  bsum[t] = sh[t] - v;            // exclusive
}

// writes off[] and turns deg region into cursors (same values)
__global__ __launch_bounds__(256) void k_scan3(const u32* __restrict__ bsum,
                                               u32* __restrict__ degcur, u32* __restrict__ off){
  __shared__ u32 sh[256];
  int t = threadIdx.x;
  int base = blockIdx.x * 1024 + t * 4;
  u32 v0 = degcur[base], v1 = degcur[base+1], v2 = degcur[base+2], v3 = degcur[base+3];
  u32 s = v0 + v1 + v2 + v3;
  sh[t] = s; __syncthreads();
  for (int o = 1; o < 256; o <<= 1){
    u32 x = (t >= o) ? sh[t-o] : 0u;
    __syncthreads();
    sh[t] += x;
    __syncthreads();
  }
  u32 ex = sh[t] - s + bsum[blockIdx.x];
  off[base]   = ex; degcur[base]   = ex; ex += v0;
  off[base+1] = ex; degcur[base+1] = ex; ex += v1;
  off[base+2] = ex; degcur[base+2] = ex; ex += v2;
  off[base+3] = ex; degcur[base+3] = ex;
  if (blockIdx.x == 0 && t == 0) off[N_NODES] = 2u * N_EDGES;
}

__global__ __launch_bounds__(256) void k_fill(const int* __restrict__ se, const int* __restrict__ re,
                                              u32* __restrict__ cur, u32* __restrict__ adj){
  int e = blockIdx.x * 256 + threadIdx.x;
  int s = se[e], r = re[e];
  adj[atomicAdd(&cur[r], 1u)] = (u32)s;
  adj[atomicAdd(&cur[s], 1u)] = (u32)r;
}

// ---------------- MFMA projection GEMMs ----------------
// S[n] = kept[n] ? bf16(x[n]*tval[n] @ dW1) : 0   (zeroing non-kept rows makes the
// down pull filter-free: summing zero rows == excluding invalid-edge messages)
__global__ __launch_bounds__(256) void k_proj_down(
    const void* __restrict__ xraw, const float* __restrict__ tval,
    const u16* __restrict__ W1T, const SelState* __restrict__ st,
    const u32* __restrict__ kept, u32* __restrict__ S)
{
  __shared__ u16 in_s[64 * 136];
  __shared__ u16 w_s[128 * 136];
  int t = threadIdx.x;
  int lane = t & 63, wv = t >> 6;
  int row0 = blockIdx.x * 64;

  if (st->is_f32){
    const float* xf = (const float*)xraw + (size_t)row0 * 128;
    for (int i = t; i < 64 * 64; i += 256){
      int r = i >> 6, q = i & 63;
      float tv = tval[row0 + r];
      float2 v = *(const float2*)(xf + (size_t)r * 128 + 2 * q);
      *(u32*)&in_s[r * 136 + 2 * q] = f2bf(v.x * tv) | (f2bf(v.y * tv) << 16);
    }
  } else {
    const u32* xw = (const u32*)xraw + (size_t)row0 * 64;
    for (int i = t; i < 64 * 64; i += 256){
      int r = i >> 6, q = i & 63;
      u32 u = xw[(size_t)r * 64 + q];
      float tv = tval[row0 + r];
      *(u32*)&in_s[r * 136 + 2 * q] = f2bf(bflo(u) * tv) | (f2bf(bfhi(u) * tv) << 16);
    }
  }
  const u32* Ww = (const u32*)W1T;
  for (int i = t; i < 128 * 64; i += 256){
    int nr = i >> 6, q = i & 63;
    *(u32*)&w_s[nr * 136 + 2 * q] = Ww[i];
  }
  __syncthreads();

  int m0 = wv * 16, mn = lane & 15, quad = lane >> 4;
  f4 acc[8];
  #pragma unroll
  for (int j = 0; j < 8; j++){ acc[j][0]=0.f; acc[j][1]=0.f; acc[j][2]=0.f; acc[j][3]=0.f; }
  wave_gemm(in_s, w_s, m0, mn, quad, acc);
  __syncthreads();

  #pragma unroll
  for (int j = 0; j < 8; j++){
    int c = j * 16 + mn;
    #pragma unroll
    for (int rg = 0; rg < 4; rg++)
      in_s[(m0 + quad * 4 + rg) * 136 + c] = (u16)f2bf(acc[j][rg]);
  }
  __syncthreads();
  for (int i = t; i < 64 * 64; i += 256){
    int r = i >> 6, q = i & 63;
    int n = row0 + r;
    u32 w = *(u32*)&in_s[r * 136 + 2 * q];
    S[(size_t)n * 64 + q] = kept[n] ? w : 0u;
  }
}

// S2[n] = bf16(R[n] @ uW1[0:128,:] + x[n] @ uW1[128:256,:])
__global__ __launch_bounds__(256) void k_proj_up(
    const u32* __restrict__ R, const void* __restrict__ xraw,
    const u16* __restrict__ W1T, const SelState* __restrict__ st,
    u32* __restrict__ S2)
{
  __shared__ u16 in_s[64 * 136];
  __shared__ u16 w_s[128 * 136];
  int t = threadIdx.x;
  int lane = t & 63, wv = t >> 6;
  int row0 = blockIdx.x * 64;
  int m0 = wv * 16, mn = lane & 15, quad = lane >> 4;

  f4 acc[8];
  #pragma unroll
  for (int j = 0; j < 8; j++){ acc[j][0]=0.f; acc[j][1]=0.f; acc[j][2]=0.f; acc[j][3]=0.f; }

  for (int ph = 0; ph < 2; ph++){
    if (ph == 0){
      for (int i = t; i < 64 * 64; i += 256){
        int r = i >> 6, q = i & 63;
        *(u32*)&in_s[r * 136 + 2 * q] = R[(size_t)(row0 + r) * 64 + q];
      }
    } else if (st->is_f32){
      const float* xf = (const float*)xraw + (size_t)row0 * 128;
      for (int i = t; i < 64 * 64; i += 256){
        int r = i >> 6, q = i & 63;
        float2 v = *(const float2*)(xf + (size_t)r * 128 + 2 * q);
        *(u32*)&in_s[r * 136 + 2 * q] = f2bf(v.x) | (f2bf(v.y) << 16);
      }
    } else {
      const u32* xw = (const u32*)xraw + (size_t)row0 * 64;
      for (int i = t; i < 64 * 64; i += 256){
        int r = i >> 6, q = i & 63;
        *(u32*)&in_s[r * 136 + 2 * q] = xw[(size_t)r * 64 + q];
      }
    }
    const u32* Ww = (const u32*)W1T;
    for (int i = t; i < 128 * 64; i += 256){
      int nr = i >> 6, q = i & 63;
      *(u32*)&w_s[nr * 136 + 2 * q] = Ww[nr * 128 + ph * 64 + q];
    }
    __syncthreads();
    wave_gemm(in_s, w_s, m0, mn, quad, acc);
    __syncthreads();
  }

  #pragma unroll
  for (int j = 0; j < 8; j++){
    int c = j * 16 + mn;
    #pragma unroll
    for (int rg = 0; rg < 4; rg++)
      in_s[(m0 + quad * 4 + rg) * 136 + c] = (u16)f2bf(acc[j][rg]);
  }
  __syncthreads();
  for (int i = t; i < 64 * 64; i += 256){
    int r = i >> 6, q = i & 63;
    S2[(size_t)(row0 + r) * 64 + q] = *(u32*)&in_s[r * 136 + 2 * q];
  }
}

// ---------------- fused CSR-pull + MFMA MLP tail ----------------
// agg[n] = sum_{m in adj[n]} Smsg[m] (f32 accum), h1=gelu(agg+b1) -> @W2 gelu -> @W3 -> LN
template<int IS_DOWN>
__global__ __launch_bounds__(256) void k_mlp(
    const u32* __restrict__ Smsg, const u32* __restrict__ off, const u32* __restrict__ adj,
    const u16* __restrict__ cb1, const u16* __restrict__ cW2T, const u16* __restrict__ cb2,
    const u16* __restrict__ cW3T, const u16* __restrict__ cb3,
    const u16* __restrict__ cg, const u16* __restrict__ cbe,
    const u32* __restrict__ kept, const SelState* __restrict__ st,
    u32* __restrict__ Rout, void* __restrict__ fout)
{
  __shared__ u16 in_s[64 * 136];
  __shared__ u16 w_s[128 * 136];   // reused as f32 out buffer [64][132]
  __shared__ float sh_mu[64], sh_rs[64];
  int t = threadIdx.x;
  int lane = t & 63, wv = t >> 6;
  int row0 = blockIdx.x * 64;
  int m0 = wv * 16, mn = lane & 15, quad = lane >> 4;

  // pull-aggregate own wave's 16 rows; lane = dword column (2 bf16 elems)
  float b1l = bf2f(cb1[2*lane]), b1h = bf2f(cb1[2*lane+1]);
  for (int rr = wv * 16; rr < wv * 16 + 16; rr++){
    int n = row0 + rr;
    float a0 = 0.f, a1 = 0.f;
    bool active = IS_DOWN ? (kept[n] != 0u) : true;
    if (active){
      u32 jb = off[n], je = off[n+1];
      u32 j = jb;
      for (; j + 4 <= je; j += 4){
        u32 e0 = adj[j], e1 = adj[j+1], e2 = adj[j+2], e3 = adj[j+3];
        u32 w0 = Smsg[(size_t)e0 * 64 + lane];
        u32 w1 = Smsg[(size_t)e1 * 64 + lane];
        u32 w2 = Smsg[(size_t)e2 * 64 + lane];
        u32 w3 = Smsg[(size_t)e3 * 64 + lane];
        a0 += bflo(w0) + bflo(w1) + bflo(w2) + bflo(w3);
        a1 += bfhi(w0) + bfhi(w1) + bfhi(w2) + bfhi(w3);
      }
      for (; j < je; j++){
        u32 m = adj[j];
        u32 w = Smsg[(size_t)m * 64 + lane];
        a0 += bflo(w); a1 += bfhi(w);
      }
    }
    *(u32*)&in_s[rr * 136 + 2 * lane] =
        f2bf(gelu_f(a0 + b1l)) | (f2bf(gelu_f(a1 + b1h)) << 16);
  }
  const u32* W2w = (const u32*)cW2T;
  for (int i = t; i < 128 * 64; i += 256){
    int nr = i >> 6, q = i & 63;
    *(u32*)&w_s[nr * 136 + 2 * q] = W2w[i];
  }
  __syncthreads();

  f4 acc[8];
  #pragma unroll
  for (int j = 0; j < 8; j++){ acc[j][0]=0.f; acc[j][1]=0.f; acc[j][2]=0.f; acc[j][3]=0.f; }
  wave_gemm(in_s, w_s, m0, mn, quad, acc);
  __syncthreads();   // everyone done reading in_s / w_s

  // h2 = gelu(acc + b2) -> in_s (own rows), restage W3T
  #pragma unroll
  for (int j = 0; j < 8; j++){
    int c = j * 16 + mn;
    float bb = bf2f(cb2[c]);
    #pragma unroll
    for (int rg = 0; rg < 4; rg++)
      in_s[(m0 + quad * 4 + rg) * 136 + c] = (u16)f2bf(gelu_f(acc[j][rg] + bb));
  }
  const u32* W3w = (const u32*)cW3T;
  for (int i = t; i < 128 * 64; i += 256){
    int nr = i >> 6, q = i & 63;
    *(u32*)&w_s[nr * 136 + 2 * q] = W3w[i];
  }
  __syncthreads();

  #pragma unroll
  for (int j = 0; j < 8; j++){ acc[j][0]=0.f; acc[j][1]=0.f; acc[j][2]=0.f; acc[j][3]=0.f; }
  wave_gemm(in_s, w_s, m0, mn, quad, acc);
  __syncthreads();   // done reading w_s; safe to reuse as f32 buffer

  float* fbuf = (float*)w_s;
  #pragma unroll
  for (int j = 0; j < 8; j++){
    int c = j * 16 + mn;
    float bb = bf2f(cb3[c]);
    #pragma unroll
    for (int rg = 0; rg < 4; rg++)
      fbuf[(m0 + quad * 4 + rg) * 132 + c] = acc[j][rg] + bb;
  }
  __syncthreads();

  { // LN stats: 4 threads per row, 64 rows
    int r = t >> 2, c0 = (t & 3) * 32;
    float s1 = 0.f, s2 = 0.f;
    #pragma unroll
    for (int i = 0; i < 32; i++){
      float v = fbuf[r * 132 + c0 + i];
      s1 += v; s2 += v * v;
    }
    s1 += __shfl_down(s1, 2, 4); s2 += __shfl_down(s2, 2, 4);
    s1 += __shfl_down(s1, 1, 4); s2 += __shfl_down(s2, 1, 4);
    if ((t & 3) == 0){
      float mu = s1 * 0.0078125f;
      float var = s2 * 0.0078125f - mu * mu;
      sh_mu[r] = mu;
      sh_rs[r] = rsqrtf(var + LN_EPS);
    }
  }
  __syncthreads();

  if (IS_DOWN){
    for (int i = t; i < 64 * 64; i += 256){
      int r = i >> 6, q = i & 63;
      int n = row0 + r;
      u32 outw = 0;
      if (kept[n]){
        float mu = sh_mu[r], rs = sh_rs[r];
        float v0 = (fbuf[r*132 + 2*q    ] - mu) * rs * bf2f(cg[2*q    ]) + bf2f(cbe[2*q    ]);
        float v1 = (fbuf[r*132 + 2*q + 1] - mu) * rs * bf2f(cg[2*q + 1]) + bf2f(cbe[2*q + 1]);
        outw = f2bf(v0) | (f2bf(v1) << 16);
      }
      Rout[(size_t)n * 64 + q] = outw;
    }
  } else {
    int isf = st->is_f32;
    for (int i = t; i < 64 * 64; i += 256){
      int r = i >> 6, q = i & 63;
      int n = row0 + r;
      float mu = sh_mu[r], rs = sh_rs[r];
      float v0 = (fbuf[r*132 + 2*q    ] - mu) * rs * bf2f(cg[2*q    ]) + bf2f(cbe[2*q    ]);
      float v1 = (fbuf[r*132 + 2*q + 1] - mu) * rs * bf2f(cg[2*q + 1]) + bf2f(cbe[2*q + 1]);
      if (isf){
        float2 v; v.x = v0; v.y = v1;
        *(float2*)((float*)fout + (size_t)n * 128 + 2*q) = v;
      } else {
        ((u32*)fout)[(size_t)n * 64 + q] = f2bf(v0) | (f2bf(v1) << 16);
      }
    }
  }
}

// ---------------- host launch ----------------

extern "C" void kernel_launch(void* const* d_in, const int* in_sizes, int n_in,
                              void* d_out, int out_size, void* d_ws, size_t ws_size,
                              hipStream_t stream)
{
  const void* x     = d_in[0];
  const int* eidx   = (const int*)d_in[1];
  const void* poolp = d_in[2];
  const int* senders = eidx;
  const int* receivers = eidx + N_EDGES;

  char* ws = (char*)d_ws;
  SelState* st = (SelState*)(ws + ST_OFF);
  u16*  canon  = (u16*) (ws + CANON_OFF);
  u32*  partial= (u32*) (ws + PART_OFF);   // radix partials; reused as bsum
  u64*  keys   = (u64*) (ws + KEYS_OFF);
  float* tval  = (float*)(ws + TVAL_OFF);
  u32*  kept   = (u32*) (ws + KEPT_OFF);
  u32*  Sbuf   = (u32*) (ws + SBUF_OFF);   // messages (down S, then up S2)
  u32*  off    = (u32*) (ws + OFF_OFF);
  u32*  adj    = (u32*) (ws + ADJ_OFF);
  u32*  degcur = (u32*) (ws + KEYS_OFF);   // deg/cursors overlay keys (dead after k_mark)
  u32*  bsum   = partial;
  u32*  R      = (u32*) d_out;             // down-conv output lives in d_out low half

  P16 ps;
  for (int i = 0; i < 16; i++) ps.q[i] = d_in[3 + i];

  k_detect<<<1, 256, 0, stream>>>((const u32*)x, st);
  k_init<<<1, 64, 0, stream>>>(st);
  k_canon<<<(C_TOT + 255) / 256, 256, 0, stream>>>(ps, st, canon);
  k_canon_t<<<(T_REGION + 255) / 256, 256, 0, stream>>>(canon);
  k_pnorm<<<1, 128, 0, stream>>>(poolp, st);
  k_score<<<N_NODES / 4, 256, 0, stream>>>(x, poolp, st, keys, tval);
  for (int pass = 0; pass < 4; pass++){
    k_histp<<<256, 256, 0, stream>>>(keys, st, partial, pass);
    k_scanp<<<1, 256, 0, stream>>>(partial, st);
  }
  k_mark<<<N_NODES / 256, 256, 0, stream>>>(keys, st, kept);
  k_tie<<<1, 256, 0, stream>>>(st, kept);

  // ---- CSR build (keys region is dead now) ----
  hipMemsetAsync(degcur, 0, (size_t)N_NODES * 4, stream);
  k_deg<<<N_EDGES / 256, 256, 0, stream>>>(senders, receivers, degcur);
  k_scan1<<<128, 256, 0, stream>>>(degcur, bsum);
  k_scan2<<<1, 128, 0, stream>>>(bsum);
  k_scan3<<<128, 256, 0, stream>>>(bsum, degcur, off);
  k_fill<<<N_EDGES / 256, 256, 0, stream>>>(senders, receivers, degcur, adj);

  // ---- down conv: project -> pull-aggregate+MLP (no atomics, no A buffer) ----
  k_proj_down<<<N_NODES / 64, 256, 0, stream>>>(x, tval, canon + CT_DW1, st, kept, Sbuf);
  k_mlp<1><<<N_NODES / 64, 256, 0, stream>>>(Sbuf, off, adj,
      canon + C_DB1, canon + CT_DW2, canon + C_DB2,
      canon + CT_DW3, canon + C_DB3, canon + C_DG, canon + C_DBE, kept, st, R, nullptr);

  // ---- up conv ----
  k_proj_up<<<N_NODES / 64, 256, 0, stream>>>(R, x, canon + CT_UW1, st, Sbuf);
  k_mlp<0><<<N_NODES / 64, 256, 0, stream>>>(Sbuf, off, adj,
      canon + C_UB1, canon + CT_UW2, canon + C_UB2,
      canon + CT_UW3, canon + C_UB3, canon + C_UG, canon + C_UBE, kept, st, nullptr, d_out);
}

// Round 2
// 631.944 us; speedup vs baseline: 1.1675x; 1.1158x over previous
//
#include <hip/hip_runtime.h>

#define N_NODES 131072
#define N_EDGES 524288
#define K_TOP   65536
#define LN_EPS  1e-5f

typedef unsigned int u32;
typedef unsigned short u16;
typedef unsigned long long u64;

typedef __attribute__((ext_vector_type(8))) short bf8;
typedef __attribute__((ext_vector_type(4))) float f4;

// ---- ws layout (requires ws >= 40 MB) ----
#define ST_OFF    0             // SelState (~52KB, reserve 64KB)
#define CANON_OFF (64u<<10)     // canon + transposed weights (~461KB) -> [64K, 576K)
#define PART_OFF  (576u<<10)    // 256x256 u32 partial hists (radix); later BSUM (512B)
#define KEYS_OFF  (1u<<20)      // keys u64[N] = 1MB; after k_mark reused as DEG/CUR u32[N]
#define TVAL_OFF  (2u<<20)      // N f32 = 512KB
#define KEPT_OFF  ((2u<<20)+(512u<<10)) // N u32 = 512KB
#define SBUF_OFF  (3u<<20)      // big buffer: N x 64 u32 = 32MB -> [3M,35M)
#define OFF_OFF   (35u<<20)     // CSR off u32[N+1] = 512KB+4
#define ADJ_OFF   (36u<<20)     // CSR adj u32[2E] = 4MB -> ends 40M

// Big-buffer ping-pong across phases (d_out doubles as scratch):
//   down: S=ws.SBUF -> k_agg<1> -> H=d_out -> k_mlp<1> -> R=ws.SBUF
//   up:   k_proj_up(R=ws) -> S2=d_out -> k_agg<0> -> H=ws.SBUF -> k_mlp<0> -> d_out
// Every stage reads/writes disjoint buffers; no inter-block races.

// canonical parameter block offsets (bf16 elements)
#define C_DW1 0
#define C_DB1 16384
#define C_DW2 16512
#define C_DB2 32896
#define C_DW3 33024
#define C_DB3 49408
#define C_DG  49536
#define C_DBE 49664
#define C_UW1 49792
#define C_UB1 82560
#define C_UW2 82688
#define C_UB2 99072
#define C_UW3 99200
#define C_UB3 115584
#define C_UG  115712
#define C_UBE 115840
#define C_TOT 115968
// transposed weights WT[n][k] appended
#define CT_DW1 115968
#define CT_DW2 132352
#define CT_DW3 148736
#define CT_UW1 165120   /* [128][256] */
#define CT_UW2 197888
#define CT_UW3 214272
#define CT_TOT 230656
#define T_REGION (CT_TOT - CT_DW1)   /* 114688 */

__device__ __forceinline__ float bflo(u32 u){ return __uint_as_float(u << 16); }
__device__ __forceinline__ float bfhi(u32 u){ return __uint_as_float(u & 0xFFFF0000u); }
__device__ __forceinline__ float bf2f(u16 v){ return __uint_as_float(((u32)v) << 16); }
__device__ __forceinline__ u32 f2bf(float f){
  u32 u = __float_as_uint(f);
  return (u + 0x7FFFu + ((u >> 16) & 1u)) >> 16;
}
__device__ __forceinline__ float gelu_f(float x){
  return 0.5f * x * (1.0f + erff(x * 0.7071067811865476f));
}

// wave-level 16x128 GEMM step over K=128: in_s rows [m0..m0+16), WT rows = out cols.
__device__ __forceinline__ void wave_gemm(const u16* in_s, const u16* w_s,
                                          int m0, int mn, int quad, f4 acc[8]){
  #pragma unroll
  for (int s = 0; s < 4; s++){
    bf8 a = *(const bf8*)(in_s + (m0 + mn) * 136 + s * 32 + quad * 8);
    #pragma unroll
    for (int j = 0; j < 8; j++){
      bf8 b = *(const bf8*)(w_s + (j * 16 + mn) * 136 + s * 32 + quad * 8);
      acc[j] = __builtin_amdgcn_mfma_f32_16x16x32_bf16(a, b, acc[j], 0, 0, 0);
    }
  }
}

struct SelState {
  u64 prefix;
  u32 krem, eqcnt;
  int is_f32;
  u32 pad;
  double inv_norm;
  u32 eqlist[4096];
  u64 eqkey[4096];
};

struct P16 { const void* q[16]; };

// ---------------- dtype detection ----------------
__global__ void k_detect(const u32* __restrict__ xw, SelState* st){
  int t = threadIdx.x;
  int cnt = 0;
  for (int i = t; i < 4096; i += 256){
    u32 w = xw[(size_t)i * 2048];
    u32 e = (w >> 23) & 0xFFu;
    if (e >= 97u && e <= 135u) cnt++;
  }
  __shared__ int sh[256];
  sh[t] = cnt; __syncthreads();
  for (int o = 128; o > 0; o >>= 1){ if (t < o) sh[t] += sh[t+o]; __syncthreads(); }
  if (t == 0) st->is_f32 = (sh[0] >= 3072) ? 1 : 0;
}

__global__ void k_init(SelState* st){
  if (threadIdx.x == 0){ st->prefix = 0; st->krem = K_TOP; st->eqcnt = 0; }
}

__global__ void k_canon(P16 ps, const SelState* __restrict__ st, u16* __restrict__ canon){
  const int off[17] = {C_DW1,C_DB1,C_DW2,C_DB2,C_DW3,C_DB3,C_DG,C_DBE,
                       C_UW1,C_UB1,C_UW2,C_UB2,C_UW3,C_UB3,C_UG,C_UBE,C_TOT};
  int i = blockIdx.x * 256 + threadIdx.x;
  if (i >= C_TOT) return;
  int seg = 0;
  #pragma unroll
  for (int s2 = 0; s2 < 16; s2++) if (i >= off[s2+1]) seg = s2 + 1;
  int j = i - off[seg];
  if (st->is_f32) canon[i] = (u16)f2bf(((const float*)ps.q[seg])[j]);
  else            canon[i] = ((const u16*)ps.q[seg])[j];
}

// build transposed weights WT[n][k] from canon W[k][n] (N==128 for all)
__global__ void k_canon_t(u16* __restrict__ canon){
  const int src[6] = {C_DW1, C_DW2, C_DW3, C_UW1, C_UW2, C_UW3};
  const int dst[7] = {CT_DW1, CT_DW2, CT_DW3, CT_UW1, CT_UW2, CT_UW3, CT_TOT};
  int i = blockIdx.x * 256 + threadIdx.x;
  if (i >= T_REGION) return;
  int g = CT_DW1 + i;
  int seg = 0;
  #pragma unroll
  for (int s2 = 0; s2 < 6; s2++) if (g >= dst[s2+1]) seg = s2 + 1;
  int loc = g - dst[seg];
  int K = (seg == 3) ? 256 : 128;
  int n = loc / K, k = loc % K;
  canon[g] = canon[src[seg] + k * 128 + n];
}

__global__ void k_pnorm(const void* __restrict__ p, SelState* st){
  int t = threadIdx.x;
  float pv = st->is_f32 ? ((const float*)p)[t] : bf2f(((const u16*)p)[t]);
  __shared__ double sh[128];
  sh[t] = (double)pv * (double)pv;
  __syncthreads();
  for (int o = 64; o > 0; o >>= 1){ if (t < o) sh[t] += sh[t+o]; __syncthreads(); }
  if (t == 0) st->inv_norm = 1.0 / sqrt(sh[0]);
}

__global__ __launch_bounds__(256) void k_score(const void* __restrict__ xraw, const void* __restrict__ praw,
                        const SelState* __restrict__ st,
                        u64* __restrict__ keys, float* __restrict__ tval){
  int t = threadIdx.x, lane = t & 63, w = t >> 6;
  int n = blockIdx.x * 4 + w;
  double d;
  if (st->is_f32){
    const float* xf = (const float*)xraw + (size_t)n * 128;
    const float* pf = (const float*)praw;
    d = (double)xf[lane] * (double)pf[lane]
      + (double)xf[64 + lane] * (double)pf[64 + lane];
  } else {
    const u32* xw = (const u32*)xraw + (size_t)n * 64;
    const u32* pw = (const u32*)praw;
    u32 xx = xw[lane], pv = pw[lane];
    d = (double)bflo(xx) * (double)bflo(pv) + (double)bfhi(xx) * (double)bfhi(pv);
  }
  for (int o = 32; o > 0; o >>= 1) d += __shfl_down(d, o, 64);
  if (lane == 0){
    double sc = d * st->inv_norm;
    u64 u = (u64)__double_as_longlong(sc);
    u64 key = (u & 0x8000000000000000ULL) ? ~u : (u | 0x8000000000000000ULL);
    keys[n] = key;
    tval[n] = tanhf((float)sc);
  }
}

// ---------------- contention-free 4-pass radix select (top 32 bits) ----------------
__global__ __launch_bounds__(256) void k_histp(const u64* __restrict__ keys,
                                               const SelState* __restrict__ st,
                                               u32* __restrict__ partial, int pass){
  __shared__ u32 h[256];
  int t = threadIdx.x;
  h[t] = 0;
  __syncthreads();
  u64 pref = st->prefix;
  int sh_d = 56 - 8 * pass;
  for (int n = blockIdx.x * 256 + t; n < N_NODES; n += 256 * 256){
    u64 k = keys[n];
    bool m = (pass == 0) ? true : ((k >> (sh_d + 8)) == pref);
    if (m) atomicAdd(&h[(u32)((k >> sh_d) & 255)], 1u);
  }
  __syncthreads();
  partial[blockIdx.x * 256 + t] = h[t];
}

__global__ void k_scanp(const u32* __restrict__ partial, SelState* st){
  __shared__ u32 tot[256];
  int t = threadIdx.x;
  u32 s = 0;
  for (int b = 0; b < 256; b++) s += partial[b * 256 + t];
  tot[t] = s;
  __syncthreads();
  if (t == 0){
    u32 target = st->krem;
    u32 cum = 0; int chosen = 255;
    for (int b = 255; b >= 0; b--){
      if (cum + tot[b] >= target){ chosen = b; break; }
      cum += tot[b];
    }
    st->prefix = (st->prefix << 8) | (u64)(u32)chosen;
    st->krem = target - cum;
  }
}

__global__ void k_mark(const u64* __restrict__ keys, SelState* st, u32* __restrict__ kept){
  int n = blockIdx.x * blockDim.x + threadIdx.x;
  u64 k = keys[n];
  u32 t32 = (u32)(k >> 32);
  u32 T = (u32)st->prefix;
  kept[n] = (t32 > T) ? 1u : 0u;
  if (t32 == T){
    u32 i = atomicAdd(&st->eqcnt, 1u);
    if (i < 4096){ st->eqlist[i] = (u32)n; st->eqkey[i] = k; }
  }
}

__global__ void k_tie(SelState* st, u32* __restrict__ kept){
  u32 m = st->eqcnt; if (m > 4096) m = 4096;
  u32 r = st->krem;
  for (u32 i = threadIdx.x; i < m; i += blockDim.x){
    u64 ki = st->eqkey[i]; u32 ii = st->eqlist[i];
    u32 rank = 0;
    for (u32 j = 0; j < m; j++){
      u64 kj = st->eqkey[j];
      rank += (kj > ki || (kj == ki && st->eqlist[j] < ii)) ? 1u : 0u;
    }
    if (rank < r) kept[ii] = 1u;
  }
}

// ---------------- CSR build (symmetrized adjacency) ----------------
__global__ __launch_bounds__(256) void k_deg(const int* __restrict__ se, const int* __restrict__ re,
                                             u32* __restrict__ deg){
  int e = blockIdx.x * 256 + threadIdx.x;
  int s = se[e], r = re[e];
  atomicAdd(&deg[s], 1u);
  atomicAdd(&deg[r], 1u);
}

__global__ __launch_bounds__(256) void k_scan1(const u32* __restrict__ deg, u32* __restrict__ bsum){
  __shared__ u32 sh[256];
  int t = threadIdx.x;
  int base = blockIdx.x * 1024 + t * 4;
  u32 s = deg[base] + deg[base+1] + deg[base+2] + deg[base+3];
  sh[t] = s; __syncthreads();
  for (int o = 128; o > 0; o >>= 1){ if (t < o) sh[t] += sh[t+o]; __syncthreads(); }
  if (t == 0) bsum[blockIdx.x] = sh[0];
}

__global__ void k_scan2(u32* __restrict__ bsum){
  __shared__ u32 sh[128];
  int t = threadIdx.x;            // 128 threads
  u32 v = bsum[t];
  sh[t] = v; __syncthreads();
  for (int o = 1; o < 128; o <<= 1){
    u32 x = (t >= o) ? sh[t-o] : 0u;
    __syncthreads();
    sh[t] += x;
    __syncthreads();
  }
  bsum[t] = sh[t] - v;            // exclusive
}

// writes off[] and turns deg region into cursors (same values)
__global__ __launch_bounds__(256) void k_scan3(const u32* __restrict__ bsum,
                                               u32* __restrict__ degcur, u32* __restrict__ off){
  __shared__ u32 sh[256];
  int t = threadIdx.x;
  int base = blockIdx.x * 1024 + t * 4;
  u32 v0 = degcur[base], v1 = degcur[base+1], v2 = degcur[base+2], v3 = degcur[base+3];
  u32 s = v0 + v1 + v2 + v3;
  sh[t] = s; __syncthreads();
  for (int o = 1; o < 256; o <<= 1){
    u32 x = (t >= o) ? sh[t-o] : 0u;
    __syncthreads();
    sh[t] += x;
    __syncthreads();
  }
  u32 ex = sh[t] - s + bsum[blockIdx.x];
  off[base]   = ex; degcur[base]   = ex; ex += v0;
  off[base+1] = ex; degcur[base+1] = ex; ex += v1;
  off[base+2] = ex; degcur[base+2] = ex; ex += v2;
  off[base+3] = ex; degcur[base+3] = ex;
  if (blockIdx.x == 0 && t == 0) off[N_NODES] = 2u * N_EDGES;
}

__global__ __launch_bounds__(256) void k_fill(const int* __restrict__ se, const int* __restrict__ re,
                                              u32* __restrict__ cur, u32* __restrict__ adj){
  int e = blockIdx.x * 256 + threadIdx.x;
  int s = se[e], r = re[e];
  adj[atomicAdd(&cur[r], 1u)] = (u32)s;
  adj[atomicAdd(&cur[s], 1u)] = (u32)r;
}

// ---------------- MFMA projection GEMMs ----------------
// S[n] = kept[n] ? bf16(x[n]*tval[n] @ dW1) : 0   (zeroing non-kept rows makes the
// down pull filter-free: summing zero rows == excluding invalid-edge messages)
__global__ __launch_bounds__(256) void k_proj_down(
    const void* __restrict__ xraw, const float* __restrict__ tval,
    const u16* __restrict__ W1T, const SelState* __restrict__ st,
    const u32* __restrict__ kept, u32* __restrict__ S)
{
  __shared__ u16 in_s[64 * 136];
  __shared__ u16 w_s[128 * 136];
  int t = threadIdx.x;
  int lane = t & 63, wv = t >> 6;
  int row0 = blockIdx.x * 64;

  if (st->is_f32){
    const float* xf = (const float*)xraw + (size_t)row0 * 128;
    for (int i = t; i < 64 * 64; i += 256){
      int r = i >> 6, q = i & 63;
      float tv = tval[row0 + r];
      float2 v = *(const float2*)(xf + (size_t)r * 128 + 2 * q);
      *(u32*)&in_s[r * 136 + 2 * q] = f2bf(v.x * tv) | (f2bf(v.y * tv) << 16);
    }
  } else {
    const u32* xw = (const u32*)xraw + (size_t)row0 * 64;
    for (int i = t; i < 64 * 64; i += 256){
      int r = i >> 6, q = i & 63;
      u32 u = xw[(size_t)r * 64 + q];
      float tv = tval[row0 + r];
      *(u32*)&in_s[r * 136 + 2 * q] = f2bf(bflo(u) * tv) | (f2bf(bfhi(u) * tv) << 16);
    }
  }
  const u32* Ww = (const u32*)W1T;
  for (int i = t; i < 128 * 64; i += 256){
    int nr = i >> 6, q = i & 63;
    *(u32*)&w_s[nr * 136 + 2 * q] = Ww[i];
  }
  __syncthreads();

  int m0 = wv * 16, mn = lane & 15, quad = lane >> 4;
  f4 acc[8];
  #pragma unroll
  for (int j = 0; j < 8; j++){ acc[j][0]=0.f; acc[j][1]=0.f; acc[j][2]=0.f; acc[j][3]=0.f; }
  wave_gemm(in_s, w_s, m0, mn, quad, acc);
  __syncthreads();

  #pragma unroll
  for (int j = 0; j < 8; j++){
    int c = j * 16 + mn;
    #pragma unroll
    for (int rg = 0; rg < 4; rg++)
      in_s[(m0 + quad * 4 + rg) * 136 + c] = (u16)f2bf(acc[j][rg]);
  }
  __syncthreads();
  for (int i = t; i < 64 * 64; i += 256){
    int r = i >> 6, q = i & 63;
    int n = row0 + r;
    u32 w = *(u32*)&in_s[r * 136 + 2 * q];
    S[(size_t)n * 64 + q] = kept[n] ? w : 0u;
  }
}

// S2[n] = bf16(R[n] @ uW1[0:128,:] + x[n] @ uW1[128:256,:])
__global__ __launch_bounds__(256) void k_proj_up(
    const u32* __restrict__ R, const void* __restrict__ xraw,
    const u16* __restrict__ W1T, const SelState* __restrict__ st,
    u32* __restrict__ S2)
{
  __shared__ u16 in_s[64 * 136];
  __shared__ u16 w_s[128 * 136];
  int t = threadIdx.x;
  int lane = t & 63, wv = t >> 6;
  int row0 = blockIdx.x * 64;
  int m0 = wv * 16, mn = lane & 15, quad = lane >> 4;

  f4 acc[8];
  #pragma unroll
  for (int j = 0; j < 8; j++){ acc[j][0]=0.f; acc[j][1]=0.f; acc[j][2]=0.f; acc[j][3]=0.f; }

  for (int ph = 0; ph < 2; ph++){
    if (ph == 0){
      for (int i = t; i < 64 * 64; i += 256){
        int r = i >> 6, q = i & 63;
        *(u32*)&in_s[r * 136 + 2 * q] = R[(size_t)(row0 + r) * 64 + q];
      }
    } else if (st->is_f32){
      const float* xf = (const float*)xraw + (size_t)row0 * 128;
      for (int i = t; i < 64 * 64; i += 256){
        int r = i >> 6, q = i & 63;
        float2 v = *(const float2*)(xf + (size_t)r * 128 + 2 * q);
        *(u32*)&in_s[r * 136 + 2 * q] = f2bf(v.x) | (f2bf(v.y) << 16);
      }
    } else {
      const u32* xw = (const u32*)xraw + (size_t)row0 * 64;
      for (int i = t; i < 64 * 64; i += 256){
        int r = i >> 6, q = i & 63;
        *(u32*)&in_s[r * 136 + 2 * q] = xw[(size_t)r * 64 + q];
      }
    }
    const u32* Ww = (const u32*)W1T;
    for (int i = t; i < 128 * 64; i += 256){
      int nr = i >> 6, q = i & 63;
      *(u32*)&w_s[nr * 136 + 2 * q] = Ww[nr * 128 + ph * 64 + q];
    }
    __syncthreads();
    wave_gemm(in_s, w_s, m0, mn, quad, acc);
    __syncthreads();
  }

  #pragma unroll
  for (int j = 0; j < 8; j++){
    int c = j * 16 + mn;
    #pragma unroll
    for (int rg = 0; rg < 4; rg++)
      in_s[(m0 + quad * 4 + rg) * 136 + c] = (u16)f2bf(acc[j][rg]);
  }
  __syncthreads();
  for (int i = t; i < 64 * 64; i += 256){
    int r = i >> 6, q = i & 63;
    S2[(size_t)(row0 + r) * 64 + q] = *(u32*)&in_s[r * 136 + 2 * q];
  }
}

// ---------------- dedicated high-occupancy pull-aggregation ----------------
// H[n] = bf16( gelu(agg[n] + b1) ), agg f32; one wave per row, 8-deep neighbor ILP.
// No LDS, no barriers -> latency hidden by TLP (16+ waves/CU).
template<int IS_DOWN>
__global__ __launch_bounds__(256, 4) void k_agg(
    const u32* __restrict__ Smsg, const u32* __restrict__ off, const u32* __restrict__ adj,
    const u16* __restrict__ cb1, const u32* __restrict__ kept,
    u32* __restrict__ H)
{
  int t = threadIdx.x, lane = t & 63, wv = t >> 6;
  float b1l = bf2f(cb1[2 * lane]), b1h = bf2f(cb1[2 * lane + 1]);
  int base = blockIdx.x * 16 + wv * 4;
  #pragma unroll 1
  for (int rr = 0; rr < 4; rr++){
    int n = base + rr;
    if (IS_DOWN && !kept[n]){ H[(size_t)n * 64 + lane] = 0u; continue; }
    u32 jb = off[n], je = off[n + 1];
    float a0 = 0.f, a1 = 0.f;
    u32 j = jb;
    for (; j + 8 <= je; j += 8){
      u32 e0 = adj[j],   e1 = adj[j+1], e2 = adj[j+2], e3 = adj[j+3];
      u32 e4 = adj[j+4], e5 = adj[j+5], e6 = adj[j+6], e7 = adj[j+7];
      u32 w0 = Smsg[(size_t)e0 * 64 + lane];
      u32 w1 = Smsg[(size_t)e1 * 64 + lane];
      u32 w2 = Smsg[(size_t)e2 * 64 + lane];
      u32 w3 = Smsg[(size_t)e3 * 64 + lane];
      u32 w4 = Smsg[(size_t)e4 * 64 + lane];
      u32 w5 = Smsg[(size_t)e5 * 64 + lane];
      u32 w6 = Smsg[(size_t)e6 * 64 + lane];
      u32 w7 = Smsg[(size_t)e7 * 64 + lane];
      a0 += ((bflo(w0) + bflo(w1)) + (bflo(w2) + bflo(w3)))
          + ((bflo(w4) + bflo(w5)) + (bflo(w6) + bflo(w7)));
      a1 += ((bfhi(w0) + bfhi(w1)) + (bfhi(w2) + bfhi(w3)))
          + ((bfhi(w4) + bfhi(w5)) + (bfhi(w6) + bfhi(w7)));
    }
    for (; j + 4 <= je; j += 4){
      u32 e0 = adj[j], e1 = adj[j+1], e2 = adj[j+2], e3 = adj[j+3];
      u32 w0 = Smsg[(size_t)e0 * 64 + lane];
      u32 w1 = Smsg[(size_t)e1 * 64 + lane];
      u32 w2 = Smsg[(size_t)e2 * 64 + lane];
      u32 w3 = Smsg[(size_t)e3 * 64 + lane];
      a0 += (bflo(w0) + bflo(w1)) + (bflo(w2) + bflo(w3));
      a1 += (bfhi(w0) + bfhi(w1)) + (bfhi(w2) + bfhi(w3));
    }
    for (; j < je; j++){
      u32 w = Smsg[(size_t)adj[j] * 64 + lane];
      a0 += bflo(w); a1 += bfhi(w);
    }
    H[(size_t)n * 64 + lane] = f2bf(gelu_f(a0 + b1l)) | (f2bf(gelu_f(a1 + b1h)) << 16);
  }
}

// ---------------- MFMA MLP tail: h1 (from H) -> @W2 gelu -> @W3 -> LN ----------------
template<int IS_DOWN>
__global__ __launch_bounds__(256) void k_mlp(
    const u32* __restrict__ H,
    const u16* __restrict__ cW2T, const u16* __restrict__ cb2,
    const u16* __restrict__ cW3T, const u16* __restrict__ cb3,
    const u16* __restrict__ cg, const u16* __restrict__ cbe,
    const u32* __restrict__ kept, const SelState* __restrict__ st,
    u32* __restrict__ Rout, void* __restrict__ fout)
{
  __shared__ u16 in_s[64 * 136];
  __shared__ u16 w_s[128 * 136];   // reused as f32 out buffer [64][132]
  __shared__ float sh_mu[64], sh_rs[64];
  int t = threadIdx.x;
  int lane = t & 63, wv = t >> 6;
  int row0 = blockIdx.x * 64;
  int m0 = wv * 16, mn = lane & 15, quad = lane >> 4;

  // stage h1 rows (streaming, coalesced) and W2T
  for (int i = t; i < 64 * 64; i += 256){
    int r = i >> 6, q = i & 63;
    *(u32*)&in_s[r * 136 + 2 * q] = H[(size_t)(row0 + r) * 64 + q];
  }
  const u32* W2w = (const u32*)cW2T;
  for (int i = t; i < 128 * 64; i += 256){
    int nr = i >> 6, q = i & 63;
    *(u32*)&w_s[nr * 136 + 2 * q] = W2w[i];
  }
  __syncthreads();

  f4 acc[8];
  #pragma unroll
  for (int j = 0; j < 8; j++){ acc[j][0]=0.f; acc[j][1]=0.f; acc[j][2]=0.f; acc[j][3]=0.f; }
  wave_gemm(in_s, w_s, m0, mn, quad, acc);
  __syncthreads();   // everyone done reading in_s / w_s

  // h2 = gelu(acc + b2) -> in_s (own rows), restage W3T
  #pragma unroll
  for (int j = 0; j < 8; j++){
    int c = j * 16 + mn;
    float bb = bf2f(cb2[c]);
    #pragma unroll
    for (int rg = 0; rg < 4; rg++)
      in_s[(m0 + quad * 4 + rg) * 136 + c] = (u16)f2bf(gelu_f(acc[j][rg] + bb));
  }
  const u32* W3w = (const u32*)cW3T;
  for (int i = t; i < 128 * 64; i += 256){
    int nr = i >> 6, q = i & 63;
    *(u32*)&w_s[nr * 136 + 2 * q] = W3w[i];
  }
  __syncthreads();

  #pragma unroll
  for (int j = 0; j < 8; j++){ acc[j][0]=0.f; acc[j][1]=0.f; acc[j][2]=0.f; acc[j][3]=0.f; }
  wave_gemm(in_s, w_s, m0, mn, quad, acc);
  __syncthreads();   // done reading w_s; safe to reuse as f32 buffer

  float* fbuf = (float*)w_s;
  #pragma unroll
  for (int j = 0; j < 8; j++){
    int c = j * 16 + mn;
    float bb = bf2f(cb3[c]);
    #pragma unroll
    for (int rg = 0; rg < 4; rg++)
      fbuf[(m0 + quad * 4 + rg) * 132 + c] = acc[j][rg] + bb;
  }
  __syncthreads();

  { // LN stats: 4 threads per row, 64 rows
    int r = t >> 2, c0 = (t & 3) * 32;
    float s1 = 0.f, s2 = 0.f;
    #pragma unroll
    for (int i = 0; i < 32; i++){
      float v = fbuf[r * 132 + c0 + i];
      s1 += v; s2 += v * v;
    }
    s1 += __shfl_down(s1, 2, 4); s2 += __shfl_down(s2, 2, 4);
    s1 += __shfl_down(s1, 1, 4); s2 += __shfl_down(s2, 1, 4);
    if ((t & 3) == 0){
      float mu = s1 * 0.0078125f;
      float var = s2 * 0.0078125f - mu * mu;
      sh_mu[r] = mu;
      sh_rs[r] = rsqrtf(var + LN_EPS);
    }
  }
  __syncthreads();

  if (IS_DOWN){
    for (int i = t; i < 64 * 64; i += 256){
      int r = i >> 6, q = i & 63;
      int n = row0 + r;
      u32 outw = 0;
      if (kept[n]){
        float mu = sh_mu[r], rs = sh_rs[r];
        float v0 = (fbuf[r*132 + 2*q    ] - mu) * rs * bf2f(cg[2*q    ]) + bf2f(cbe[2*q    ]);
        float v1 = (fbuf[r*132 + 2*q + 1] - mu) * rs * bf2f(cg[2*q + 1]) + bf2f(cbe[2*q + 1]);
        outw = f2bf(v0) | (f2bf(v1) << 16);
      }
      Rout[(size_t)n * 64 + q] = outw;
    }
  } else {
    int isf = st->is_f32;
    for (int i = t; i < 64 * 64; i += 256){
      int r = i >> 6, q = i & 63;
      int n = row0 + r;
      float mu = sh_mu[r], rs = sh_rs[r];
      float v0 = (fbuf[r*132 + 2*q    ] - mu) * rs * bf2f(cg[2*q    ]) + bf2f(cbe[2*q    ]);
      float v1 = (fbuf[r*132 + 2*q + 1] - mu) * rs * bf2f(cg[2*q + 1]) + bf2f(cbe[2*q + 1]);
      if (isf){
        float2 v; v.x = v0; v.y = v1;
        *(float2*)((float*)fout + (size_t)n * 128 + 2*q) = v;
      } else {
        ((u32*)fout)[(size_t)n * 64 + q] = f2bf(v0) | (f2bf(v1) << 16);
      }
    }
  }
}

// ---------------- host launch ----------------

extern "C" void kernel_launch(void* const* d_in, const int* in_sizes, int n_in,
                              void* d_out, int out_size, void* d_ws, size_t ws_size,
                              hipStream_t stream)
{
  const void* x     = d_in[0];
  const int* eidx   = (const int*)d_in[1];
  const void* poolp = d_in[2];
  const int* senders = eidx;
  const int* receivers = eidx + N_EDGES;

  char* ws = (char*)d_ws;
  SelState* st = (SelState*)(ws + ST_OFF);
  u16*  canon  = (u16*) (ws + CANON_OFF);
  u32*  partial= (u32*) (ws + PART_OFF);   // radix partials; reused as bsum
  u64*  keys   = (u64*) (ws + KEYS_OFF);
  float* tval  = (float*)(ws + TVAL_OFF);
  u32*  kept   = (u32*) (ws + KEPT_OFF);
  u32*  Sbuf   = (u32*) (ws + SBUF_OFF);   // 32MB ws big-buffer
  u32*  off    = (u32*) (ws + OFF_OFF);
  u32*  adj    = (u32*) (ws + ADJ_OFF);
  u32*  degcur = (u32*) (ws + KEYS_OFF);   // deg/cursors overlay keys (dead after k_mark)
  u32*  bsum   = partial;
  u32*  Dbuf   = (u32*) d_out;             // 32MB d_out scratch region (low half if f32)

  P16 ps;
  for (int i = 0; i < 16; i++) ps.q[i] = d_in[3 + i];

  k_detect<<<1, 256, 0, stream>>>((const u32*)x, st);
  k_init<<<1, 64, 0, stream>>>(st);
  k_canon<<<(C_TOT + 255) / 256, 256, 0, stream>>>(ps, st, canon);
  k_canon_t<<<(T_REGION + 255) / 256, 256, 0, stream>>>(canon);
  k_pnorm<<<1, 128, 0, stream>>>(poolp, st);
  k_score<<<N_NODES / 4, 256, 0, stream>>>(x, poolp, st, keys, tval);
  for (int pass = 0; pass < 4; pass++){
    k_histp<<<256, 256, 0, stream>>>(keys, st, partial, pass);
    k_scanp<<<1, 256, 0, stream>>>(partial, st);
  }
  k_mark<<<N_NODES / 256, 256, 0, stream>>>(keys, st, kept);
  k_tie<<<1, 256, 0, stream>>>(st, kept);

  // ---- CSR build (keys region is dead now) ----
  hipMemsetAsync(degcur, 0, (size_t)N_NODES * 4, stream);
  k_deg<<<N_EDGES / 256, 256, 0, stream>>>(senders, receivers, degcur);
  k_scan1<<<128, 256, 0, stream>>>(degcur, bsum);
  k_scan2<<<1, 128, 0, stream>>>(bsum);
  k_scan3<<<128, 256, 0, stream>>>(bsum, degcur, off);
  k_fill<<<N_EDGES / 256, 256, 0, stream>>>(senders, receivers, degcur, adj);

  // ---- down conv: S(ws) -> agg H(d_out) -> MLP -> R(ws) ----
  k_proj_down<<<N_NODES / 64, 256, 0, stream>>>(x, tval, canon + CT_DW1, st, kept, Sbuf);
  k_agg<1><<<N_NODES / 16, 256, 0, stream>>>(Sbuf, off, adj, canon + C_DB1, kept, Dbuf);
  k_mlp<1><<<N_NODES / 64, 256, 0, stream>>>(Dbuf,
      canon + CT_DW2, canon + C_DB2, canon + CT_DW3, canon + C_DB3,
      canon + C_DG, canon + C_DBE, kept, st, Sbuf, nullptr);

  // ---- up conv: R(ws) -> S2(d_out) -> agg H(ws) -> MLP -> d_out ----
  k_proj_up<<<N_NODES / 64, 256, 0, stream>>>(Sbuf, x, canon + CT_UW1, st, Dbuf);
  k_agg<0><<<N_NODES / 16, 256, 0, stream>>>(Dbuf, off, adj, canon + C_UB1, kept, Sbuf);
  k_mlp<0><<<N_NODES / 64, 256, 0, stream>>>(Sbuf,
      canon + CT_UW2, canon + C_UB2, canon + CT_UW3, canon + C_UB3,
      canon + C_UG, canon + C_UBE, kept, st, nullptr, d_out);
}